// Round 5
// baseline (328.662 us; speedup 1.0000x reference)
//
#include <hip/hip_runtime.h>
#include <math.h>

// ---------------------------------------------------------------------------
// NetVLAD on gfx950.
// conv1/conv2: implicit GEMM, v_mfma_f32_16x16x32_bf16, 128x128 tile, BK=64,
//   2 blocks/CU. T3/T4 pipeline: W dbuf, counted vmcnt(4), W(s+2) in flight
//   across barriers, halo(cc+1) FIFO-first at tap==8, T5 setprio.
//   kh-split step: 16 kh0-MFMAs before the lgkmcnt(0) WAR drain, 16 kh1-MFMAs
//   (register-only) after the barrier covering DMA issue.
//   conv2 (MODE 1) epilogue: fused expand — stage the 128x128 tile into the
//   now-free LDS (Ep[128][136] bf16, 16B-aligned rows, +4-bank rotation),
//   then coalesced transposed writes: 8x uint4 (xeb) + 16x float4 (xenc) per
//   thread. (Round-4 scalar [c][pix] stores caused 88 MB HBM writes + L2
//   thrash — partial-sector 2B stores; this restores full-line coverage.)
// assign_softmax + vlad: 4-deep LDS multibuffer, counted vmcnt.
// prep_all: fused zero_border+misc+xform+wt_prep.
// Fragment layouts (HW-verified): A/B: idx=lane&15, k=(lane>>4)*8+j;
// C/D: col=lane&15 (B idx), row=(lane>>4)*4+reg (A idx).
// ---------------------------------------------------------------------------

typedef __bf16 bf16x8 __attribute__((ext_vector_type(8)));
typedef float f32x4 __attribute__((ext_vector_type(4)));

#define GLDS16(gp, lp)                                                  \
  __builtin_amdgcn_global_load_lds(                                     \
      (const __attribute__((address_space(1))) void*)(gp),              \
      (__attribute__((address_space(3))) void*)(lp), 16, 0, 0)

// ---------------- conv as implicit GEMM, halo-tiled, BK=64 -----------------
// grid (128 pixel-tiles, 4 o-tiles), block 256 = 4 waves (2x2)
// MODE 0: BN+ReLU -> padded NHWC bf16 (hpad).
// MODE 1: xebT bf16 [n][pix][512] + xenc fp32 [n][c][pix] + xeb bf16 [n][c][pix]
template <int MODE>
__global__ __launch_bounds__(256) void conv_gemm(
    const __bf16* __restrict__ in,  // padded NHWC bf16 [16][34][34][512]
    const __bf16* __restrict__ wt,  // prepacked+swizzled [512][72*64]
    const float* __restrict__ scale, const float* __restrict__ shift,
    __bf16* __restrict__ outp, float* __restrict__ xenc,
    __bf16* __restrict__ xeb) {
  // one buffer: Hl = SM[0,16128), Wl = SM[16128,32512); MODE-1 epilogue
  // reuses SM as Ep[128][136] (17408 elem) after the final barrier.
  __shared__ __align__(16) __bf16 SM[32512];  // 65,024 B
  __bf16* Hl = SM;
  __bf16* Wl = SM + 16128;

  const int t = threadIdx.x;
  const int bx = blockIdx.x, oT = blockIdx.y;
  const int lane = t & 63, wid = t >> 6;
  const int l16 = lane & 15, q = lane >> 4;
  const int wrow = wid >> 1, wcol = wid & 1;

  const int n = bx >> 3;
  const int trow0 = (bx & 7) * 4;  // first pixel row of this 128-pixel tile

  // ---- W staging: 4 chunks/thread; Wl[buf][row][phys8] = row*64 + phys*8
  const int swr = t >> 3, sp = t & 7;
  const __bf16* wsrc[4];
#pragma unroll
  for (int i = 0; i < 4; ++i)
    wsrc[i] = wt + (size_t)(oT * 128 + 32 * i + swr) * 4608 + sp * 8;

  // ---- halo staging: 8 chunks/thread over 6 rows x 42 cols x 8 c8-chunks
  const __bf16* inb = in + (size_t)n * (1156 * 512);
  const __bf16* hsrc[8];
  bool hval[8];
#pragma unroll
  for (int i = 0; i < 8; ++i) {
    const int jj = t + 256 * i;
    hval[i] = jj < 2016;
    const int hr = jj / 336;
    const int hrem = jj - hr * 336;
    const int hw = hrem >> 3, hc8 = hrem & 7;
    hsrc[i] = inb + ((size_t)((trow0 + hr) * 34 + hw)) * 512 +
              (hc8 ^ (hw & 7)) * 8;
  }

  // ---- fragment read constants
  const int c0 = (q ^ (l16 & 7)) * 8;
  const int c1 = ((4 + q) ^ (l16 & 7)) * 8;
  int aoff[4], prow_[4], pcol_[4];
#pragma unroll
  for (int i = 0; i < 4; ++i) {
    aoff[i] = (wrow * 64 + i * 16 + l16) * 64;
    const int p = wcol * 64 + i * 16 + l16;
    prow_[i] = p >> 5;
    pcol_[i] = p & 31;
  }

  f32x4 acc[4][4];
#pragma unroll
  for (int i = 0; i < 4; ++i)
#pragma unroll
    for (int j = 0; j < 4; ++j) acc[i][j] = (f32x4){0.f, 0.f, 0.f, 0.f};

  // ---- prologue: halo(cc=0), W(step0)->Wl[0], W(step1)->Wl[1] ------------
  // step s has (cc,tap) = (s/9, s%9); woffs = (tap*8+cc)*64.
#pragma unroll
  for (int i = 0; i < 8; ++i)
    if (hval[i]) GLDS16(hsrc[i], Hl + (t + 256 * i) * 8);
#pragma unroll
  for (int i = 0; i < 4; ++i)
    GLDS16(wsrc[i], Wl + (t + 256 * i) * 8);  // step0: woffs=0
#pragma unroll
  for (int i = 0; i < 4; ++i)
    GLDS16(wsrc[i] + 512, Wl + 8192 + (t + 256 * i) * 8);  // step1: woffs=512
  // outstanding: halo(8) + W0(4) + W1(4). Wait halo+W0; keep W1 in flight.
  asm volatile("s_waitcnt vmcnt(4)" ::: "memory");
  __builtin_amdgcn_s_barrier();

  int tap = 0, dh = 0, dw = 0, cc = 0;  // step s
  int tap2 = 2, cc2 = 0;                // step s+2 (prefetch target)

#pragma unroll 1
  for (int s = 0; s < 72; ++s) {
    const int buf = (s & 1) << 13;  // 0 or 8192 elements
    const __bf16* Wb = Wl + buf;

    // A: fragment reads for step s (kh0 group first, then kh1)
    bf16x8 aw0[4], aw1[4], bp0[4], bp1[4];
    int rbs[4], xrs[4];
#pragma unroll
    for (int i = 0; i < 4; ++i) aw0[i] = *(const bf16x8*)&Wb[aoff[i] + c0];
#pragma unroll
    for (int i = 0; i < 4; ++i) {
      const int col = pcol_[i] + dw;
      rbs[i] = (prow_[i] + dh) * 2688 + col * 64;
      xrs[i] = col & 7;
      bp0[i] = *(const bf16x8*)&Hl[rbs[i] + (q ^ xrs[i]) * 8];
    }
#pragma unroll
    for (int i = 0; i < 4; ++i) aw1[i] = *(const bf16x8*)&Wb[aoff[i] + c1];
#pragma unroll
    for (int i = 0; i < 4; ++i)
      bp1[i] = *(const bf16x8*)&Hl[rbs[i] + ((4 + q) ^ xrs[i]) * 8];

    // B: MFMA kh0 — compiler waits only the kh0 subset of ds_reads;
    //    kh1 reads keep draining underneath.
    __builtin_amdgcn_s_setprio(1);
#pragma unroll
    for (int mt = 0; mt < 4; ++mt)
#pragma unroll
      for (int nt = 0; nt < 4; ++nt)
        acc[mt][nt] = __builtin_amdgcn_mfma_f32_16x16x32_bf16(
            aw0[mt], bp0[nt], acc[mt][nt], 0, 0, 0);
    __builtin_amdgcn_s_setprio(0);

    // C: all 12 reads landed in regs (cross-wave WAR vs incoming DMA).
    asm volatile("s_waitcnt lgkmcnt(0)" ::: "memory");
    __builtin_amdgcn_sched_barrier(0);
    __builtin_amdgcn_s_barrier();

    // D: issue next-halo FIRST (FIFO: so vmcnt(4) below covers it), then
    //    W(s+2) into the buffer step s just finished reading.
    if (tap == 8 && cc < 7) {
#pragma unroll
      for (int i = 0; i < 8; ++i)
        if (hval[i]) GLDS16(hsrc[i] + (cc + 1) * 64, Hl + (t + 256 * i) * 8);
    }
    if (s < 70) {
      const int woffs2 = (tap2 * 8 + cc2) * 64;
#pragma unroll
      for (int i = 0; i < 4; ++i)
        GLDS16(wsrc[i] + woffs2, Wl + buf + (t + 256 * i) * 8);
    }

    // E: MFMA kh1 (register-only; covers DMA issue)
    __builtin_amdgcn_s_setprio(1);
#pragma unroll
    for (int mt = 0; mt < 4; ++mt)
#pragma unroll
      for (int nt = 0; nt < 4; ++nt)
        acc[mt][nt] = __builtin_amdgcn_mfma_f32_16x16x32_bf16(
            aw1[mt], bp1[nt], acc[mt][nt], 0, 0, 0);
    __builtin_amdgcn_s_setprio(0);

    // F/G: counted wait — drain {W(s+1), halo-if-issued}; W(s+2) stays in
    // flight across the barrier. Tail drains fully.
    if (s < 70)
      asm volatile("s_waitcnt vmcnt(4)" ::: "memory");
    else
      asm volatile("s_waitcnt vmcnt(0)" ::: "memory");
    __builtin_amdgcn_s_barrier();

    // advance step / prefetch counters
    ++tap;
    ++dw;
    if (dw == 3) {
      dw = 0;
      ++dh;
    }
    if (tap == 9) {
      tap = 0;
      dh = 0;
      dw = 0;
      ++cc;
    }
    if (++tap2 == 9) {
      tap2 = 0;
      ++cc2;
    }
  }

  // ---- epilogue ----
  if (MODE == 0) {
#pragma unroll
    for (int nt = 0; nt < 4; ++nt) {
      const int m_l = wcol * 64 + nt * 16 + l16;
      const int mg2 = bx * 128 + m_l;
      const int n2 = mg2 >> 10, pix2 = mg2 & 1023;
#pragma unroll
      for (int mt = 0; mt < 4; ++mt) {
        const int ob = oT * 128 + wrow * 64 + mt * 16 + q * 4;
        f32x4 v = acc[mt][nt];
        union {
          __bf16 b[4];
          uint2 u;
        } pk;
        const f32x4 sc = *(const f32x4*)&scale[ob];
        const f32x4 sh = *(const f32x4*)&shift[ob];
#pragma unroll
        for (int r = 0; r < 4; ++r)
          pk.b[r] = (__bf16)fmaxf(v[r] * sc[r] + sh[r], 0.f);
        __bf16* dst = outp +
                      ((size_t)n2 * 1156 + ((pix2 >> 5) + 1) * 34 +
                       ((pix2 & 31) + 1)) * 512 + ob;
        *(uint2*)dst = pk.u;
      }
    }
  } else {
    // fused expand: stage tile into free LDS, then coalesced writes.
    __bf16* Ep = SM;  // [128 ch][136 pix-stride] bf16, 34,816 B
#pragma unroll
    for (int nt = 0; nt < 4; ++nt) {
      const int pix_l = wcol * 64 + nt * 16 + l16;   // 0..127 in tile
      const int pix2 = (bx & 7) * 128 + pix_l;       // 0..1023 in image
#pragma unroll
      for (int mt = 0; mt < 4; ++mt) {
        const int chl = wrow * 64 + mt * 16 + q * 4;  // 0..124
        const int ob = oT * 128 + chl;
        f32x4 v = acc[mt][nt];
        union {
          __bf16 b[4];
          uint2 u;
        } pk;
#pragma unroll
        for (int r = 0; r < 4; ++r) pk.b[r] = (__bf16)v[r];
        *(uint2*)(outp + ((size_t)n * 1024 + pix2) * 512 + ob) = pk.u;
#pragma unroll
        for (int r = 0; r < 4; ++r) Ep[(chl + r) * 136 + pix_l] = pk.b[r];
      }
    }
    __syncthreads();
    // transposed coalesced writes: thread -> (ch = t>>1, 64-pix half)
    const int ch = t >> 1;
    const int half = (t & 1) * 64;
    const size_t rb =
        ((size_t)n * 512 + oT * 128 + ch) * 1024 + (bx & 7) * 128 + half;
    union {
      __bf16 b[64];
      uint4 u[8];
    } row;
#pragma unroll
    for (int j = 0; j < 8; ++j)
      *(bf16x8*)&row.b[j * 8] = *(const bf16x8*)&Ep[ch * 136 + half + j * 8];
#pragma unroll
    for (int j = 0; j < 8; ++j) *(uint4*)&xeb[rb + j * 8] = row.u[j];
#pragma unroll
    for (int j = 0; j < 16; ++j) {
      float4 f = {(float)row.b[j * 4], (float)row.b[j * 4 + 1],
                  (float)row.b[j * 4 + 2], (float)row.b[j * 4 + 3]};
      *(float4*)&xenc[rb + j * 4] = f;
    }
  }
}

// ---------------- soft-assign + softmax (MFMA, 4-deep pipeline) ------------
__global__ __launch_bounds__(256) void assign_softmax(
    const __bf16* __restrict__ xebT, const __bf16* __restrict__ watb,
    __bf16* __restrict__ saPb, float* __restrict__ S) {
  __shared__ __align__(16) __bf16 Al[4][64 * 32];
  __shared__ __align__(16) __bf16 Wlb[4][64 * 32];
  __shared__ float Sl[64];
  const int t = threadIdx.x;
  const int pt = blockIdx.x, n = blockIdx.y;
  const int lane = t & 63, wid = t >> 6;
  const int l16 = lane & 15, q = lane >> 4;
  if (t < 64) Sl[t] = 0.f;

  const int arow = t >> 2;  // pixel row 0..63
  const __bf16* asrc = xebT + ((size_t)n * 1024 + pt * 64 + arow) * 512 +
                       ((t & 3) ^ ((arow >> 1) & 3)) * 8;
  const __bf16* wsrc = watb + (size_t)(t >> 2) * 512 + (t & 3) * 8;
  const int ldsb = wid * 512;
  const int sw = (q ^ ((l16 >> 1) & 3)) * 8;
  const int pnoff = (t >> 2) * 32 + (t & 3) * 8;

  f32x4 acc[4];
#pragma unroll
  for (int i = 0; i < 4; ++i) acc[i] = (f32x4){0.f, 0.f, 0.f, 0.f};
  float pn = 0.f;

  // prologue: issue tiles 0..2 (2 loads each)
#pragma unroll
  for (int p = 0; p < 3; ++p) {
    GLDS16(asrc + p * 32, (__bf16*)Al[p] + ldsb);
    GLDS16(wsrc + p * 32, (__bf16*)Wlb[p] + ldsb);
  }
  asm volatile("s_waitcnt vmcnt(4)" ::: "memory");  // tile0 done; 1,2 fly
  __builtin_amdgcn_s_barrier();

#pragma unroll 1
  for (int kc = 0; kc < 16; ++kc) {
    const __bf16* Ab = Al[kc & 3];
    const __bf16* Wb = Wlb[kc & 3];
    // A: register reads of this tile
    bf16x8 pv = *(const bf16x8*)&Ab[pnoff];
    bf16x8 pf = *(const bf16x8*)&Ab[(wid * 16 + l16) * 32 + sw];
    bf16x8 wf[4];
#pragma unroll
    for (int ka = 0; ka < 4; ++ka)
      wf[ka] = *(const bf16x8*)&Wb[(ka * 16 + l16) * 32 + sw];
    // B: all waves' reads landed before buffer reuse
    asm volatile("s_waitcnt lgkmcnt(0)" ::: "memory");
    __builtin_amdgcn_sched_barrier(0);
    __builtin_amdgcn_s_barrier();
    // C: issue tile kc+3 into buf (kc+3)&3 (read-complete since iter kc-1)
    if (kc + 3 < 16) {
      GLDS16(asrc + (kc + 3) * 32, (__bf16*)Al[(kc + 3) & 3] + ldsb);
      GLDS16(wsrc + (kc + 3) * 32, (__bf16*)Wlb[(kc + 3) & 3] + ldsb);
    }
    // D: compute
#pragma unroll
    for (int j = 0; j < 8; ++j) {
      float f = (float)pv[j];
      pn = fmaf(f, f, pn);
    }
#pragma unroll
    for (int ka = 0; ka < 4; ++ka)
      acc[ka] =
          __builtin_amdgcn_mfma_f32_16x16x32_bf16(wf[ka], pf, acc[ka], 0, 0, 0);
    // E/F: counted wait — tile kc+1 ready; kc+2, kc+3 stay in flight
    if (kc < 13)
      asm volatile("s_waitcnt vmcnt(4)" ::: "memory");
    else
      asm volatile("s_waitcnt vmcnt(0)" ::: "memory");
    __builtin_amdgcn_s_barrier();
  }
  pn += __shfl_xor(pn, 1);
  pn += __shfl_xor(pn, 2);
  const float rn = 1.0f / fmaxf(sqrtf(__shfl(pn, l16 * 4)), 1e-12f);

  float sc[16];
  float m = -3.4e38f;
#pragma unroll
  for (int ka = 0; ka < 4; ++ka)
#pragma unroll
    for (int r = 0; r < 4; ++r) {
      float v = acc[ka][r] * rn;
      sc[ka * 4 + r] = v;
      m = fmaxf(m, v);
    }
  m = fmaxf(m, __shfl_xor(m, 16));
  m = fmaxf(m, __shfl_xor(m, 32));
  float s = 0.f;
#pragma unroll
  for (int j = 0; j < 16; ++j) {
    sc[j] = __expf(sc[j] - m);
    s += sc[j];
  }
  s += __shfl_xor(s, 16);
  s += __shfl_xor(s, 32);
  const float inv = 1.0f / s;
  const int pixg = pt * 64 + wid * 16 + l16;
#pragma unroll
  for (int j = 0; j < 16; ++j) {
    const int k = (j >> 2) * 16 + q * 4 + (j & 3);
    float sa = sc[j] * inv;
    sc[j] = sa;
    saPb[((size_t)n * 64 + k) * 1024 + pixg] = (__bf16)(sa * rn);
  }
#pragma unroll
  for (int j = 0; j < 16; ++j) {
    float v = sc[j];
    v += __shfl_xor(v, 1);
    v += __shfl_xor(v, 2);
    v += __shfl_xor(v, 4);
    v += __shfl_xor(v, 8);
    sc[j] = v;
  }
  if (l16 == 0) {
#pragma unroll
    for (int j = 0; j < 16; ++j)
      atomicAdd(&Sl[(j >> 2) * 16 + q * 4 + (j & 3)], sc[j]);
  }
  __syncthreads();
  if (t < 64) atomicAdd(&S[n * 64 + t], Sl[t]);
}

// ---------------- VLAD aggregation: bf16 MFMA GEMM (4-deep pipeline) -------
__global__ __launch_bounds__(256) void vlad_gemm(
    const __bf16* __restrict__ saPb, const __bf16* __restrict__ xeb,
    float* __restrict__ vpart) {
  __shared__ __align__(16) __bf16 Al[4][64 * 32];
  __shared__ __align__(16) __bf16 Bl[4][128 * 32];

  const int t = threadIdx.x;
  const int cT = blockIdx.x, n = blockIdx.y, ks = blockIdx.z;
  const int lane = t & 63, wid = t >> 6;
  const int l16 = lane & 15, q = lane >> 4;
  const int wrow = wid >> 1, wcol = wid & 1;

  const int ar = t >> 2, acp = t & 3;
  const __bf16* asrc = saPb + (size_t)n * 65536 + (size_t)ar * 1024 + ks * 256 +
                       (acp ^ ((ar >> 1) & 3)) * 8;
  const int br0 = t >> 2, bcp0 = t & 3;
  const int br1 = (t + 256) >> 2, bcp1 = t & 3;
  const __bf16* bsrc0 = xeb + (size_t)n * 524288 +
                        (size_t)(cT * 128 + br0) * 1024 + ks * 256 +
                        (bcp0 ^ ((br0 >> 1) & 3)) * 8;
  const __bf16* bsrc1 = xeb + (size_t)n * 524288 +
                        (size_t)(cT * 128 + br1) * 1024 + ks * 256 +
                        (bcp1 ^ ((br1 >> 1) & 3)) * 8;

  const int ldsb = wid * 512;
  const int sw = (q ^ ((l16 >> 1) & 3)) * 8;

  f32x4 acc[2][4];
#pragma unroll
  for (int i = 0; i < 2; ++i)
#pragma unroll
    for (int j = 0; j < 4; ++j) acc[i][j] = (f32x4){0.f, 0.f, 0.f, 0.f};

  // prologue: issue tiles 0..2 (3 loads each)
#pragma unroll
  for (int p = 0; p < 3; ++p) {
    GLDS16(asrc + p * 32, (__bf16*)Al[p] + ldsb);
    GLDS16(bsrc0 + p * 32, (__bf16*)Bl[p] + ldsb);
    GLDS16(bsrc1 + p * 32, (__bf16*)Bl[p] + 2048 + ldsb);
  }
  asm volatile("s_waitcnt vmcnt(6)" ::: "memory");  // tile0 done; 1,2 fly
  __builtin_amdgcn_s_barrier();

#pragma unroll 1
  for (int kc = 0; kc < 8; ++kc) {
    const __bf16* Ab = Al[kc & 3];
    const __bf16* Bb = Bl[kc & 3];
    // A: register reads
    bf16x8 af[2], bf[4];
#pragma unroll
    for (int i = 0; i < 2; ++i)
      af[i] = *(const bf16x8*)&Ab[(wrow * 32 + i * 16 + l16) * 32 + sw];
#pragma unroll
    for (int i = 0; i < 4; ++i)
      bf[i] = *(const bf16x8*)&Bb[(wcol * 64 + i * 16 + l16) * 32 + sw];
    // B: reads landed before buffer reuse
    asm volatile("s_waitcnt lgkmcnt(0)" ::: "memory");
    __builtin_amdgcn_sched_barrier(0);
    __builtin_amdgcn_s_barrier();
    // C: issue tile kc+3
    if (kc + 3 < 8) {
      GLDS16(asrc + (kc + 3) * 32, (__bf16*)Al[(kc + 3) & 3] + ldsb);
      GLDS16(bsrc0 + (kc + 3) * 32, (__bf16*)Bl[(kc + 3) & 3] + ldsb);
      GLDS16(bsrc1 + (kc + 3) * 32, (__bf16*)Bl[(kc + 3) & 3] + 2048 + ldsb);
    }
    // D: MFMA
#pragma unroll
    for (int mt = 0; mt < 2; ++mt)
#pragma unroll
      for (int nt = 0; nt < 4; ++nt)
        acc[mt][nt] = __builtin_amdgcn_mfma_f32_16x16x32_bf16(
            af[mt], bf[nt], acc[mt][nt], 0, 0, 0);
    // E/F: counted wait — tile kc+1 ready; kc+2, kc+3 stay in flight
    if (kc < 5)
      asm volatile("s_waitcnt vmcnt(6)" ::: "memory");
    else
      asm volatile("s_waitcnt vmcnt(0)" ::: "memory");
    __builtin_amdgcn_s_barrier();
  }

  float* vp = vpart + (size_t)(ks * 16 + n) * 32768;
#pragma unroll
  for (int mt = 0; mt < 2; ++mt) {
    const int krow = wrow * 32 + mt * 16 + q * 4;
#pragma unroll
    for (int nt = 0; nt < 4; ++nt) {
      const int ccol = cT * 128 + wcol * 64 + nt * 16 + l16;
#pragma unroll
      for (int r = 0; r < 4; ++r)
        vp[(size_t)(krow + r) * 512 + ccol] = acc[mt][nt][r];
    }
  }
}

// ---------------- intra-norm (sums 4 K-split partials) ---------------------
__global__ __launch_bounds__(64) void intra_norm(float* __restrict__ vraw,
                                                 const float* __restrict__ vpart,
                                                 const float* __restrict__ S,
                                                 const float* __restrict__ cent,
                                                 float* __restrict__ gss) {
  const int b = blockIdx.x;  // n*64 + k
  const int n = b >> 6, k = b & 63;
  const int lane = threadIdx.x;
  const float s = S[b];
  float v[8];
  float ss = 0.f;
#pragma unroll
  for (int j = 0; j < 8; ++j) {
    const int c = lane * 8 + j;
    const size_t off = (size_t)b * 512 + c;
    float val = vpart[off] + vpart[524288 + off] + vpart[2 * 524288 + off] +
                vpart[3 * 524288 + off] - s * cent[k * 512 + c];
    v[j] = val;
    ss += val * val;
  }
#pragma unroll
  for (int off = 1; off < 64; off <<= 1) ss += __shfl_xor(ss, off);
  const float rn = 1.0f / fmaxf(sqrtf(ss), 1e-12f);
#pragma unroll
  for (int j = 0; j < 8; ++j) vraw[(size_t)b * 512 + lane * 8 + j] = v[j] * rn;
  if (lane == 0) atomicAdd(&gss[n], ss * rn * rn);
}

__global__ __launch_bounds__(256) void finalize(const float* __restrict__ vraw,
                                                const float* __restrict__ gss,
                                                float* __restrict__ out) {
  const int id = blockIdx.x * 256 + threadIdx.x;
  const int n = id >> 15;
  out[id] = vraw[id] * (1.0f / fmaxf(sqrtf(gss[n]), 1e-12f));
}

// ---------------- fused prep: zero_border + misc + xform + wt_prep ---------
// grid layout: [0,1056) zero-border, [1056,1191) misc, [1191,1703) xform,
// [1703,2727) wt_prep. All independent writes; fusing overlaps them across
// CUs and drops 3 launch gaps.
__global__ __launch_bounds__(256) void prep_all(
    const float* __restrict__ x, const float* __restrict__ w1,
    const float* __restrict__ w2, const float* __restrict__ g,
    const float* __restrict__ b, const float* __restrict__ m,
    const float* __restrict__ v, const float* __restrict__ wA,
    __bf16* __restrict__ xpad, __bf16* __restrict__ hpad,
    __bf16* __restrict__ wt1, __bf16* __restrict__ wt2,
    float* __restrict__ scale, float* __restrict__ shift,
    __bf16* __restrict__ watb, float* __restrict__ Sz) {
  __shared__ float Lw[4608];
  const int bx = blockIdx.x;
  const int t = threadIdx.x;

  if (bx < 1056) {
    // ---- zero the 132-pixel pad ring of xpad/hpad ----
    const int which = bx >= 528;
    const int id = (which ? bx - 528 : bx) * 256 + t;  // 0..135167
    const int n = id / 8448;
    const int rem = id - n * 8448;
    const int pb = rem >> 6;  // 0..131 border pixel
    const int c8 = rem & 63;
    int h, w;
    if (pb < 34) {
      h = 0;
      w = pb;
    } else if (pb < 68) {
      h = 33;
      w = pb - 34;
    } else {
      const int r2 = pb - 68;
      h = 1 + (r2 >> 1);
      w = (r2 & 1) * 33;
    }
    __bf16* base = which ? hpad : xpad;
    *(uint4*)(base + ((size_t)n * 1156 + h * 34 + w) * 512 + c8 * 8) =
        (uint4){0u, 0u, 0u, 0u};
  } else if (bx < 1191) {
    // ---- misc: BN fold, watb swizzle, S zero ----
    const int i = (bx - 1056) * 256 + t;
    if (i < 512) {
      float sc = g[i] / sqrtf(v[i] + 1e-5f);
      scale[i] = sc;
      shift[i] = b[i] - m[i] * sc;
    } else if (i < 512 + 32768) {
      const int id = i - 512;
      const int k = id >> 9, j = id & 511;
      const int kt = j >> 5, cpos = (j >> 3) & 3, e = j & 7;
      const int c = kt * 32 + (cpos ^ ((k >> 1) & 3)) * 8 + e;
      watb[(size_t)k * 512 + j] = (__bf16)wA[(size_t)k * 512 + c];
    } else if (i < 512 + 32768 + 1040) {
      Sz[i - (512 + 32768)] = 0.f;
    }
  } else if (bx < 1703) {
    // ---- xform: x (fp32 NCHW) -> xpad (bf16 NHWC padded) ----
    const int bb = bx - 1191;
    const int n = bb >> 5, h = bb & 31;
    const int w = t & 31, cg = t >> 5;
    const float* src = x + ((size_t)n * 512 + cg * 64) * 1024 + h * 32 + w;
    __bf16* dst =
        xpad + ((size_t)n * 1156 + (h + 1) * 34 + (w + 1)) * 512 + cg * 64;
    float fv[64];
#pragma unroll
    for (int j = 0; j < 64; ++j) fv[j] = src[j * 1024];  // all loads in flight
#pragma unroll
    for (int jj = 0; jj < 8; ++jj) {
      union {
        __bf16 b8[8];
        uint4 u;
      } pk;
#pragma unroll
      for (int j = 0; j < 8; ++j) pk.b8[j] = (__bf16)fv[jj * 8 + j];
      *(uint4*)(dst + jj * 8) = pk.u;
    }
  } else {
    // ---- wt_prep: OIHW fp32 -> [o][kt*64 + p*8 + e] bf16, swizzle baked ---
    const int bb = bx - 1703;  // 0..1023
    const int o = bb & 511;
    const float* w = (bb >> 9) ? w2 : w1;
    __bf16* wt = (bb >> 9) ? wt2 : wt1;
#pragma unroll
    for (int i = 0; i < 18; ++i)
      Lw[t + 256 * i] = w[(size_t)o * 4608 + t + 256 * i];
    __syncthreads();
#pragma unroll
    for (int i = 0; i < 18; ++i) {
      const int idk = t + 256 * i;
      const int kt = idk >> 6;
      const int p = (idk >> 3) & 7, e = idk & 7;
      const int logical = p ^ (o & 7);
      const int k2 = kt * 64 + logical * 8 + e;
      const int tap = k2 >> 9, ci = k2 & 511;
      wt[(size_t)o * 4608 + idk] = (__bf16)Lw[ci * 9 + tap];
    }
  }
}

// ---------------------------------------------------------------------------
extern "C" void kernel_launch(void* const* d_in, const int* in_sizes, int n_in,
                              void* d_out, int out_size, void* d_ws,
                              size_t ws_size, hipStream_t stream) {
  const float* x = (const float*)d_in[0];
  const float* w1 = (const float*)d_in[1];
  const float* gam = (const float*)d_in[2];
  const float* bet = (const float*)d_in[3];
  const float* mean = (const float*)d_in[4];
  const float* var = (const float*)d_in[5];
  const float* w2 = (const float*)d_in[6];
  const float* wA = (const float*)d_in[7];
  const float* cent = (const float*)d_in[8];
  float* out = (float*)d_out;

  char* ws = (char*)d_ws;
  __bf16* Wt1 = (__bf16*)(ws + 0);          // 4,718,592 (dead after conv1)
  __bf16* Wt2 = (__bf16*)(ws + 4718592);    // 4,718,592 (dead after conv2)
  __bf16* xpad = (__bf16*)(ws + 9437184);   // 18,939,904 (dead after conv1)
  __bf16* xebT = (__bf16*)(ws + 9437184);   // alias: 16,777,216 (conv2 out)
  __bf16* saPb = (__bf16*)(ws + 26214400);  // 2,097,152
  __bf16* hpad = (__bf16*)(ws + 28377088);  // 18,939,904 (dead after conv2)
  __bf16* xeb = (__bf16*)(ws + 28377088);   // alias: 16,777,216 (conv2 out)
  float* vpart = (float*)(ws + 0);          // alias Wt1/2: 8,388,608
  float* vraw = (float*)(ws + 8388608);     // alias: 2,097,152
  float* scale = (float*)(ws + 47316992);   // 2048 B
  float* shift = (float*)(ws + 47319040);   // 2048 B
  __bf16* watb = (__bf16*)(ws + 47321088);  // 65,536 B
  float* S = (float*)(ws + 47386624);       // 4096 B
  float* gss = (float*)(ws + 47390720);     // 64 B

  float* xenc = out + 524288;  // output 1 (x_enc, fp32 NCHW)

  prep_all<<<2727, 256, 0, stream>>>(x, w1, w2, gam, bet, mean, var, wA, xpad,
                                     hpad, Wt1, Wt2, scale, shift, watb, S);

  conv_gemm<0><<<dim3(128, 4), 256, 0, stream>>>(xpad, Wt1, scale, shift, hpad,
                                                 nullptr, nullptr);
  conv_gemm<1><<<dim3(128, 4), 256, 0, stream>>>(hpad, Wt2, nullptr, nullptr,
                                                 xebT, xenc, xeb);

  assign_softmax<<<dim3(16, 16), 256, 0, stream>>>(xebT, watb, saPb, S);
  vlad_gemm<<<dim3(4, 16, 4), 256, 0, stream>>>(saPb, xeb, vpart);
  intra_norm<<<1024, 64, 0, stream>>>(vraw, vpart, S, cent, gss);
  finalize<<<2048, 256, 0, stream>>>(vraw, gss, out);
}

// Round 6
// 319.687 us; speedup vs baseline: 1.0281x; 1.0281x over previous
//
#include <hip/hip_runtime.h>
#include <math.h>

// ---------------------------------------------------------------------------
// NetVLAD on gfx950.
// conv1/conv2: implicit GEMM, v_mfma_f32_16x16x32_bf16, 128x128 tile, BK=64,
//   2 blocks/CU. T3/T4 pipeline, T5 setprio, kh-split MFMA halves.
//   NEW: W TRIPLE-buffer (Wl[3][128*64], 48 KB; total LDS 81,408 B — still
//   2 blocks/CU). Step s reads buf s%3, DMAs W(s+2) into (s+2)%3 =
//   (s-1)%3, whose reads finished before the previous end-of-step barrier
//   (kh1's operand waits imply full lgkm drain). So the per-step
//   lgkmcnt(0)+barrier WAR fence is needed only at tap==8 (halo rewrite).
//   Barriers/step: 2 -> ~1.1.
//   conv2 writes xebT ONLY (round-4/5 fused-expand regressed: xebT L2
//   write-combining broke + xeb-aliases-hpad race. Reverted.)
// post_conv: fused assign_softmax (256 blocks, first) + expand_x (2048
//   blocks) — independent work, one launch, latency/BW overlap.
// vlad: 4-deep LDS multibuffer, counted vmcnt. prep_all: fused prep.
// Fragment layouts (HW-verified): A/B: idx=lane&15, k=(lane>>4)*8+j;
// C/D: col=lane&15 (B idx), row=(lane>>4)*4+reg (A idx).
// ---------------------------------------------------------------------------

typedef __bf16 bf16x8 __attribute__((ext_vector_type(8)));
typedef float f32x4 __attribute__((ext_vector_type(4)));

#define GLDS16(gp, lp)                                                  \
  __builtin_amdgcn_global_load_lds(                                     \
      (const __attribute__((address_space(1))) void*)(gp),              \
      (__attribute__((address_space(3))) void*)(lp), 16, 0, 0)

// ---------------- conv as implicit GEMM, halo-tiled, BK=64 -----------------
// grid (128 pixel-tiles, 4 o-tiles), block 256 = 4 waves (2x2)
// MODE 0: BN+ReLU -> padded NHWC bf16 (hpad).
// MODE 1: xebT bf16 [n][pix][512] (c-contiguous), no BN.
template <int MODE>
__global__ __launch_bounds__(256) void conv_gemm(
    const __bf16* __restrict__ in,  // padded NHWC bf16 [16][34][34][512]
    const __bf16* __restrict__ wt,  // prepacked+swizzled [512][72*64]
    const float* __restrict__ scale, const float* __restrict__ shift,
    __bf16* __restrict__ outp) {
  __shared__ __align__(16) __bf16 Hl[6 * 42 * 64];   // 32,256 B
  __shared__ __align__(16) __bf16 Wl[3 * 128 * 64];  // 49,152 B (triple)

  const int t = threadIdx.x;
  const int bx = blockIdx.x, oT = blockIdx.y;
  const int lane = t & 63, wid = t >> 6;
  const int l16 = lane & 15, q = lane >> 4;
  const int wrow = wid >> 1, wcol = wid & 1;

  const int n = bx >> 3;
  const int trow0 = (bx & 7) * 4;  // first pixel row of this 128-pixel tile

  // ---- W staging: 4 chunks/thread; Wl[buf][row][phys8] = row*64 + phys*8
  const int swr = t >> 3, sp = t & 7;
  const __bf16* wsrc[4];
#pragma unroll
  for (int i = 0; i < 4; ++i)
    wsrc[i] = wt + (size_t)(oT * 128 + 32 * i + swr) * 4608 + sp * 8;

  // ---- halo staging: 8 chunks/thread over 6 rows x 42 cols x 8 c8-chunks
  const __bf16* inb = in + (size_t)n * (1156 * 512);
  const __bf16* hsrc[8];
  bool hval[8];
#pragma unroll
  for (int i = 0; i < 8; ++i) {
    const int jj = t + 256 * i;
    hval[i] = jj < 2016;
    const int hr = jj / 336;
    const int hrem = jj - hr * 336;
    const int hw = hrem >> 3, hc8 = hrem & 7;
    hsrc[i] = inb + ((size_t)((trow0 + hr) * 34 + hw)) * 512 +
              (hc8 ^ (hw & 7)) * 8;
  }

  // ---- fragment read constants
  const int c0 = (q ^ (l16 & 7)) * 8;
  const int c1 = ((4 + q) ^ (l16 & 7)) * 8;
  int aoff[4], prow_[4], pcol_[4];
#pragma unroll
  for (int i = 0; i < 4; ++i) {
    aoff[i] = (wrow * 64 + i * 16 + l16) * 64;
    const int p = wcol * 64 + i * 16 + l16;
    prow_[i] = p >> 5;
    pcol_[i] = p & 31;
  }

  f32x4 acc[4][4];
#pragma unroll
  for (int i = 0; i < 4; ++i)
#pragma unroll
    for (int j = 0; j < 4; ++j) acc[i][j] = (f32x4){0.f, 0.f, 0.f, 0.f};

  // ---- prologue: halo(cc=0), W(step0)->buf0, W(step1)->buf1 --------------
  // step s has (cc,tap) = (s/9, s%9); woffs = (tap*8+cc)*64.
#pragma unroll
  for (int i = 0; i < 8; ++i)
    if (hval[i]) GLDS16(hsrc[i], Hl + (t + 256 * i) * 8);
#pragma unroll
  for (int i = 0; i < 4; ++i)
    GLDS16(wsrc[i], Wl + (t + 256 * i) * 8);  // step0: woffs=0
#pragma unroll
  for (int i = 0; i < 4; ++i)
    GLDS16(wsrc[i] + 512, Wl + 8192 + (t + 256 * i) * 8);  // step1: woffs=512
  // outstanding: halo(8) + W0(4) + W1(4). Wait halo+W0; keep W1 in flight.
  asm volatile("s_waitcnt vmcnt(4)" ::: "memory");
  __builtin_amdgcn_s_barrier();

  int tap = 0, dh = 0, dw = 0, cc = 0;  // step s
  int tap2 = 2, cc2 = 0;                // step s+2 (prefetch target)
  int cur = 0;                          // s % 3

#pragma unroll 1
  for (int s = 0; s < 72; ++s) {
    const __bf16* Wb = Wl + cur * 8192;

    // A: fragment reads for step s (kh0 group first, then kh1)
    bf16x8 aw0[4], aw1[4], bp0[4], bp1[4];
    int rbs[4], xrs[4];
#pragma unroll
    for (int i = 0; i < 4; ++i) aw0[i] = *(const bf16x8*)&Wb[aoff[i] + c0];
#pragma unroll
    for (int i = 0; i < 4; ++i) {
      const int col = pcol_[i] + dw;
      rbs[i] = (prow_[i] + dh) * 2688 + col * 64;
      xrs[i] = col & 7;
      bp0[i] = *(const bf16x8*)&Hl[rbs[i] + (q ^ xrs[i]) * 8];
    }
#pragma unroll
    for (int i = 0; i < 4; ++i) aw1[i] = *(const bf16x8*)&Wb[aoff[i] + c1];
#pragma unroll
    for (int i = 0; i < 4; ++i)
      bp1[i] = *(const bf16x8*)&Hl[rbs[i] + ((4 + q) ^ xrs[i]) * 8];

    // B: MFMA kh0 (compiler waits only the kh0-subset of ds_reads)
    __builtin_amdgcn_s_setprio(1);
#pragma unroll
    for (int mt = 0; mt < 4; ++mt)
#pragma unroll
      for (int nt = 0; nt < 4; ++nt)
        acc[mt][nt] = __builtin_amdgcn_mfma_f32_16x16x32_bf16(
            aw0[mt], bp0[nt], acc[mt][nt], 0, 0, 0);
    __builtin_amdgcn_s_setprio(0);

    // C: WAR fence ONLY when the halo buffer gets rewritten (tap==8).
    //    The W-DMA below targets (s+2)%3 == (s-1)%3, whose reads completed
    //    before the previous end-of-step barrier (kh1 implies lgkm drain).
    if (tap == 8) {
      asm volatile("s_waitcnt lgkmcnt(0)" ::: "memory");
      __builtin_amdgcn_sched_barrier(0);
      __builtin_amdgcn_s_barrier();
      if (cc < 7) {
#pragma unroll
        for (int i = 0; i < 8; ++i)
          if (hval[i]) GLDS16(hsrc[i] + (cc + 1) * 64, Hl + (t + 256 * i) * 8);
      }
    }
    if (s < 70) {
      int b2 = cur + 2;
      if (b2 >= 3) b2 -= 3;
      const int woffs2 = (tap2 * 8 + cc2) * 64;
#pragma unroll
      for (int i = 0; i < 4; ++i)
        GLDS16(wsrc[i] + woffs2, Wl + b2 * 8192 + (t + 256 * i) * 8);
    }

    // E: MFMA kh1 (register-only; covers DMA issue)
    __builtin_amdgcn_s_setprio(1);
#pragma unroll
    for (int mt = 0; mt < 4; ++mt)
#pragma unroll
      for (int nt = 0; nt < 4; ++nt)
        acc[mt][nt] = __builtin_amdgcn_mfma_f32_16x16x32_bf16(
            aw1[mt], bp1[nt], acc[mt][nt], 0, 0, 0);
    __builtin_amdgcn_s_setprio(0);

    // F/G: counted wait — drain {W(s+1), halo-if-issued}; W(s+2) stays in
    // flight across the barrier. Tail drains fully.
    if (s < 70)
      asm volatile("s_waitcnt vmcnt(4)" ::: "memory");
    else
      asm volatile("s_waitcnt vmcnt(0)" ::: "memory");
    __builtin_amdgcn_s_barrier();

    // advance step / prefetch counters
    ++tap;
    ++dw;
    if (dw == 3) {
      dw = 0;
      ++dh;
    }
    if (tap == 9) {
      tap = 0;
      dh = 0;
      dw = 0;
      ++cc;
    }
    if (++tap2 == 9) {
      tap2 = 0;
      ++cc2;
    }
    if (++cur == 3) cur = 0;
  }

  // ---- epilogue ----
#pragma unroll
  for (int nt = 0; nt < 4; ++nt) {
    const int m_l = wcol * 64 + nt * 16 + l16;
    const int mg2 = bx * 128 + m_l;
    const int n2 = mg2 >> 10, pix2 = mg2 & 1023;
#pragma unroll
    for (int mt = 0; mt < 4; ++mt) {
      const int ob = oT * 128 + wrow * 64 + mt * 16 + q * 4;
      f32x4 v = acc[mt][nt];
      union {
        __bf16 b[4];
        uint2 u;
      } pk;
      if (MODE == 0) {
        const f32x4 sc = *(const f32x4*)&scale[ob];
        const f32x4 sh = *(const f32x4*)&shift[ob];
#pragma unroll
        for (int r = 0; r < 4; ++r)
          pk.b[r] = (__bf16)fmaxf(v[r] * sc[r] + sh[r], 0.f);
        __bf16* dst = outp +
                      ((size_t)n2 * 1156 + ((pix2 >> 5) + 1) * 34 +
                       ((pix2 & 31) + 1)) * 512 + ob;
        *(uint2*)dst = pk.u;
      } else {
#pragma unroll
        for (int r = 0; r < 4; ++r) pk.b[r] = (__bf16)v[r];
        __bf16* dst = outp + ((size_t)n2 * 1024 + pix2) * 512 + ob;
        *(uint2*)dst = pk.u;
      }
    }
  }
}

// ---------------- fused post-conv2: assign_softmax + expand_x --------------
// bx < 256: assign_softmax (latency-bound long pole — dispatched first).
// bx >= 256: expand_x (BW-bound, fills remaining CUs).
__global__ __launch_bounds__(256) void post_conv(
    const __bf16* __restrict__ xebT, const __bf16* __restrict__ watb,
    __bf16* __restrict__ saPb, float* __restrict__ S,
    float* __restrict__ xenc, __bf16* __restrict__ xeb) {
  __shared__ __align__(16) __bf16 Al[4][64 * 32];
  __shared__ __align__(16) __bf16 Wlb[4][64 * 32];
  __shared__ float Sl[64];
  const int t = threadIdx.x;
  const int bx0 = blockIdx.x;

  if (bx0 < 256) {
    // ======== assign_softmax (4-deep pipeline) ========
    const int pt = bx0 & 15, n = bx0 >> 4;
    const int lane = t & 63, wid = t >> 6;
    const int l16 = lane & 15, q = lane >> 4;
    if (t < 64) Sl[t] = 0.f;

    const int arow = t >> 2;  // pixel row 0..63
    const __bf16* asrc = xebT + ((size_t)n * 1024 + pt * 64 + arow) * 512 +
                         ((t & 3) ^ ((arow >> 1) & 3)) * 8;
    const __bf16* wsrc = watb + (size_t)(t >> 2) * 512 + (t & 3) * 8;
    const int ldsb = wid * 512;
    const int sw = (q ^ ((l16 >> 1) & 3)) * 8;
    const int pnoff = (t >> 2) * 32 + (t & 3) * 8;

    f32x4 acc[4];
#pragma unroll
    for (int i = 0; i < 4; ++i) acc[i] = (f32x4){0.f, 0.f, 0.f, 0.f};
    float pn = 0.f;

#pragma unroll
    for (int p = 0; p < 3; ++p) {
      GLDS16(asrc + p * 32, (__bf16*)Al[p] + ldsb);
      GLDS16(wsrc + p * 32, (__bf16*)Wlb[p] + ldsb);
    }
    asm volatile("s_waitcnt vmcnt(4)" ::: "memory");
    __builtin_amdgcn_s_barrier();

#pragma unroll 1
    for (int kc = 0; kc < 16; ++kc) {
      const __bf16* Ab = Al[kc & 3];
      const __bf16* Wb = Wlb[kc & 3];
      bf16x8 pv = *(const bf16x8*)&Ab[pnoff];
      bf16x8 pf = *(const bf16x8*)&Ab[(wid * 16 + l16) * 32 + sw];
      bf16x8 wf[4];
#pragma unroll
      for (int ka = 0; ka < 4; ++ka)
        wf[ka] = *(const bf16x8*)&Wb[(ka * 16 + l16) * 32 + sw];
      asm volatile("s_waitcnt lgkmcnt(0)" ::: "memory");
      __builtin_amdgcn_sched_barrier(0);
      __builtin_amdgcn_s_barrier();
      if (kc + 3 < 16) {
        GLDS16(asrc + (kc + 3) * 32, (__bf16*)Al[(kc + 3) & 3] + ldsb);
        GLDS16(wsrc + (kc + 3) * 32, (__bf16*)Wlb[(kc + 3) & 3] + ldsb);
      }
#pragma unroll
      for (int j = 0; j < 8; ++j) {
        float f = (float)pv[j];
        pn = fmaf(f, f, pn);
      }
#pragma unroll
      for (int ka = 0; ka < 4; ++ka)
        acc[ka] = __builtin_amdgcn_mfma_f32_16x16x32_bf16(wf[ka], pf, acc[ka],
                                                          0, 0, 0);
      if (kc < 13)
        asm volatile("s_waitcnt vmcnt(4)" ::: "memory");
      else
        asm volatile("s_waitcnt vmcnt(0)" ::: "memory");
      __builtin_amdgcn_s_barrier();
    }
    pn += __shfl_xor(pn, 1);
    pn += __shfl_xor(pn, 2);
    const float rn = 1.0f / fmaxf(sqrtf(__shfl(pn, l16 * 4)), 1e-12f);

    float sc[16];
    float m = -3.4e38f;
#pragma unroll
    for (int ka = 0; ka < 4; ++ka)
#pragma unroll
      for (int r = 0; r < 4; ++r) {
        float v = acc[ka][r] * rn;
        sc[ka * 4 + r] = v;
        m = fmaxf(m, v);
      }
    m = fmaxf(m, __shfl_xor(m, 16));
    m = fmaxf(m, __shfl_xor(m, 32));
    float s = 0.f;
#pragma unroll
    for (int j = 0; j < 16; ++j) {
      sc[j] = __expf(sc[j] - m);
      s += sc[j];
    }
    s += __shfl_xor(s, 16);
    s += __shfl_xor(s, 32);
    const float inv = 1.0f / s;
    const int pixg = pt * 64 + wid * 16 + l16;
#pragma unroll
    for (int j = 0; j < 16; ++j) {
      const int k = (j >> 2) * 16 + q * 4 + (j & 3);
      float sa = sc[j] * inv;
      sc[j] = sa;
      saPb[((size_t)n * 64 + k) * 1024 + pixg] = (__bf16)(sa * rn);
    }
#pragma unroll
    for (int j = 0; j < 16; ++j) {
      float v = sc[j];
      v += __shfl_xor(v, 1);
      v += __shfl_xor(v, 2);
      v += __shfl_xor(v, 4);
      v += __shfl_xor(v, 8);
      sc[j] = v;
    }
    if (l16 == 0) {
#pragma unroll
      for (int j = 0; j < 16; ++j)
        atomicAdd(&Sl[(j >> 2) * 16 + q * 4 + (j & 3)], sc[j]);
    }
    __syncthreads();
    if (t < 64) atomicAdd(&S[n * 64 + t], Sl[t]);
  } else {
    // ======== expand_x: xebT [pix][c] -> xenc fp32 [c][pix] + xeb bf16 ====
    const int e = bx0 - 256;
    const int cc = e & 7, ptile = (e >> 3) & 15, n = e >> 7;
    __bf16* Ll = (__bf16*)Al;  // 8 KB carve
    const int p0 = ptile * 64, c0 = cc * 64;
#pragma unroll
    for (int i = 0; i < 2; ++i) {
      const int u = t * 2 + i;
      const int pix = u >> 3, c8 = u & 7;
      uint4 v = *(const uint4*)&xebT[((size_t)n * 1024 + p0 + pix) * 512 + c0 +
                                     c8 * 8];
      *(uint4*)&Ll[pix * 64 + (c8 ^ (pix & 7)) * 8] = v;
    }
    __syncthreads();
    const int c = t >> 2, g = t & 3;
    union {
      float f[4];
      float4 v;
    } fv[4];
    union {
      __bf16 b[16];
      uint4 u[2];
    } bv;
#pragma unroll
    for (int r = 0; r < 16; ++r) {
      const int pix = g * 16 + r;
      __bf16 b = Ll[pix * 64 + ((c >> 3) ^ (pix & 7)) * 8 + (c & 7)];
      bv.b[r] = b;
      fv[r >> 2].f[r & 3] = (float)b;
    }
    float* fd = xenc + ((size_t)n * 512 + c0 + c) * 1024 + p0 + g * 16;
#pragma unroll
    for (int r = 0; r < 4; ++r) *(float4*)(fd + r * 4) = fv[r].v;
    __bf16* bd = xeb + ((size_t)n * 512 + c0 + c) * 1024 + p0 + g * 16;
    *(uint4*)bd = bv.u[0];
    *(uint4*)(bd + 8) = bv.u[1];
  }
}

// ---------------- VLAD aggregation: bf16 MFMA GEMM (4-deep pipeline) -------
__global__ __launch_bounds__(256) void vlad_gemm(
    const __bf16* __restrict__ saPb, const __bf16* __restrict__ xeb,
    float* __restrict__ vpart) {
  __shared__ __align__(16) __bf16 Al[4][64 * 32];
  __shared__ __align__(16) __bf16 Bl[4][128 * 32];

  const int t = threadIdx.x;
  const int cT = blockIdx.x, n = blockIdx.y, ks = blockIdx.z;
  const int lane = t & 63, wid = t >> 6;
  const int l16 = lane & 15, q = lane >> 4;
  const int wrow = wid >> 1, wcol = wid & 1;

  const int ar = t >> 2, acp = t & 3;
  const __bf16* asrc = saPb + (size_t)n * 65536 + (size_t)ar * 1024 + ks * 256 +
                       (acp ^ ((ar >> 1) & 3)) * 8;
  const int br0 = t >> 2, bcp0 = t & 3;
  const int br1 = (t + 256) >> 2, bcp1 = t & 3;
  const __bf16* bsrc0 = xeb + (size_t)n * 524288 +
                        (size_t)(cT * 128 + br0) * 1024 + ks * 256 +
                        (bcp0 ^ ((br0 >> 1) & 3)) * 8;
  const __bf16* bsrc1 = xeb + (size_t)n * 524288 +
                        (size_t)(cT * 128 + br1) * 1024 + ks * 256 +
                        (bcp1 ^ ((br1 >> 1) & 3)) * 8;

  const int ldsb = wid * 512;
  const int sw = (q ^ ((l16 >> 1) & 3)) * 8;

  f32x4 acc[2][4];
#pragma unroll
  for (int i = 0; i < 2; ++i)
#pragma unroll
    for (int j = 0; j < 4; ++j) acc[i][j] = (f32x4){0.f, 0.f, 0.f, 0.f};

  // prologue: issue tiles 0..2 (3 loads each)
#pragma unroll
  for (int p = 0; p < 3; ++p) {
    GLDS16(asrc + p * 32, (__bf16*)Al[p] + ldsb);
    GLDS16(bsrc0 + p * 32, (__bf16*)Bl[p] + ldsb);
    GLDS16(bsrc1 + p * 32, (__bf16*)Bl[p] + 2048 + ldsb);
  }
  asm volatile("s_waitcnt vmcnt(6)" ::: "memory");  // tile0 done; 1,2 fly
  __builtin_amdgcn_s_barrier();

#pragma unroll 1
  for (int kc = 0; kc < 8; ++kc) {
    const __bf16* Ab = Al[kc & 3];
    const __bf16* Bb = Bl[kc & 3];
    // A: register reads
    bf16x8 af[2], bf[4];
#pragma unroll
    for (int i = 0; i < 2; ++i)
      af[i] = *(const bf16x8*)&Ab[(wrow * 32 + i * 16 + l16) * 32 + sw];
#pragma unroll
    for (int i = 0; i < 4; ++i)
      bf[i] = *(const bf16x8*)&Bb[(wcol * 64 + i * 16 + l16) * 32 + sw];
    // B: reads landed before buffer reuse
    asm volatile("s_waitcnt lgkmcnt(0)" ::: "memory");
    __builtin_amdgcn_sched_barrier(0);
    __builtin_amdgcn_s_barrier();
    // C: issue tile kc+3
    if (kc + 3 < 8) {
      GLDS16(asrc + (kc + 3) * 32, (__bf16*)Al[(kc + 3) & 3] + ldsb);
      GLDS16(bsrc0 + (kc + 3) * 32, (__bf16*)Bl[(kc + 3) & 3] + ldsb);
      GLDS16(bsrc1 + (kc + 3) * 32, (__bf16*)Bl[(kc + 3) & 3] + 2048 + ldsb);
    }
    // D: MFMA
#pragma unroll
    for (int mt = 0; mt < 2; ++mt)
#pragma unroll
      for (int nt = 0; nt < 4; ++nt)
        acc[mt][nt] = __builtin_amdgcn_mfma_f32_16x16x32_bf16(
            af[mt], bf[nt], acc[mt][nt], 0, 0, 0);
    // E/F: counted wait — tile kc+1 ready; kc+2, kc+3 stay in flight
    if (kc < 5)
      asm volatile("s_waitcnt vmcnt(6)" ::: "memory");
    else
      asm volatile("s_waitcnt vmcnt(0)" ::: "memory");
    __builtin_amdgcn_s_barrier();
  }

  float* vp = vpart + (size_t)(ks * 16 + n) * 32768;
#pragma unroll
  for (int mt = 0; mt < 2; ++mt) {
    const int krow = wrow * 32 + mt * 16 + q * 4;
#pragma unroll
    for (int nt = 0; nt < 4; ++nt) {
      const int ccol = cT * 128 + wcol * 64 + nt * 16 + l16;
#pragma unroll
      for (int r = 0; r < 4; ++r)
        vp[(size_t)(krow + r) * 512 + ccol] = acc[mt][nt][r];
    }
  }
}

// ---------------- intra-norm (sums 4 K-split partials) ---------------------
__global__ __launch_bounds__(64) void intra_norm(float* __restrict__ vraw,
                                                 const float* __restrict__ vpart,
                                                 const float* __restrict__ S,
                                                 const float* __restrict__ cent,
                                                 float* __restrict__ gss) {
  const int b = blockIdx.x;  // n*64 + k
  const int n = b >> 6, k = b & 63;
  const int lane = threadIdx.x;
  const float s = S[b];
  float v[8];
  float ss = 0.f;
#pragma unroll
  for (int j = 0; j < 8; ++j) {
    const int c = lane * 8 + j;
    const size_t off = (size_t)b * 512 + c;
    float val = vpart[off] + vpart[524288 + off] + vpart[2 * 524288 + off] +
                vpart[3 * 524288 + off] - s * cent[k * 512 + c];
    v[j] = val;
    ss += val * val;
  }
#pragma unroll
  for (int off = 1; off < 64; off <<= 1) ss += __shfl_xor(ss, off);
  const float rn = 1.0f / fmaxf(sqrtf(ss), 1e-12f);
#pragma unroll
  for (int j = 0; j < 8; ++j) vraw[(size_t)b * 512 + lane * 8 + j] = v[j] * rn;
  if (lane == 0) atomicAdd(&gss[n], ss * rn * rn);
}

__global__ __launch_bounds__(256) void finalize(const float* __restrict__ vraw,
                                                const float* __restrict__ gss,
                                                float* __restrict__ out) {
  const int id = blockIdx.x * 256 + threadIdx.x;
  const int n = id >> 15;
  out[id] = vraw[id] * (1.0f / fmaxf(sqrtf(gss[n]), 1e-12f));
}

// ---------------- fused prep: zero_border + misc + xform + wt_prep ---------
// grid layout: [0,1056) zero-border, [1056,1191) misc, [1191,1703) xform,
// [1703,2727) wt_prep. All independent writes; fusing overlaps them across
// CUs and drops 3 launch gaps.
__global__ __launch_bounds__(256) void prep_all(
    const float* __restrict__ x, const float* __restrict__ w1,
    const float* __restrict__ w2, const float* __restrict__ g,
    const float* __restrict__ b, const float* __restrict__ m,
    const float* __restrict__ v, const float* __restrict__ wA,
    __bf16* __restrict__ xpad, __bf16* __restrict__ hpad,
    __bf16* __restrict__ wt1, __bf16* __restrict__ wt2,
    float* __restrict__ scale, float* __restrict__ shift,
    __bf16* __restrict__ watb, float* __restrict__ Sz) {
  __shared__ float Lw[4608];
  const int bx = blockIdx.x;
  const int t = threadIdx.x;

  if (bx < 1056) {
    // ---- zero the 132-pixel pad ring of xpad/hpad ----
    const int which = bx >= 528;
    const int id = (which ? bx - 528 : bx) * 256 + t;  // 0..135167
    const int n = id / 8448;
    const int rem = id - n * 8448;
    const int pb = rem >> 6;  // 0..131 border pixel
    const int c8 = rem & 63;
    int h, w;
    if (pb < 34) {
      h = 0;
      w = pb;
    } else if (pb < 68) {
      h = 33;
      w = pb - 34;
    } else {
      const int r2 = pb - 68;
      h = 1 + (r2 >> 1);
      w = (r2 & 1) * 33;
    }
    __bf16* base = which ? hpad : xpad;
    *(uint4*)(base + ((size_t)n * 1156 + h * 34 + w) * 512 + c8 * 8) =
        (uint4){0u, 0u, 0u, 0u};
  } else if (bx < 1191) {
    // ---- misc: BN fold, watb swizzle, S zero ----
    const int i = (bx - 1056) * 256 + t;
    if (i < 512) {
      float sc = g[i] / sqrtf(v[i] + 1e-5f);
      scale[i] = sc;
      shift[i] = b[i] - m[i] * sc;
    } else if (i < 512 + 32768) {
      const int id = i - 512;
      const int k = id >> 9, j = id & 511;
      const int kt = j >> 5, cpos = (j >> 3) & 3, e = j & 7;
      const int c = kt * 32 + (cpos ^ ((k >> 1) & 3)) * 8 + e;
      watb[(size_t)k * 512 + j] = (__bf16)wA[(size_t)k * 512 + c];
    } else if (i < 512 + 32768 + 1040) {
      Sz[i - (512 + 32768)] = 0.f;
    }
  } else if (bx < 1703) {
    // ---- xform: x (fp32 NCHW) -> xpad (bf16 NHWC padded) ----
    const int bb = bx - 1191;
    const int n = bb >> 5, h = bb & 31;
    const int w = t & 31, cg = t >> 5;
    const float* src = x + ((size_t)n * 512 + cg * 64) * 1024 + h * 32 + w;
    __bf16* dst =
        xpad + ((size_t)n * 1156 + (h + 1) * 34 + (w + 1)) * 512 + cg * 64;
    float fv[64];
#pragma unroll
    for (int j = 0; j < 64; ++j) fv[j] = src[j * 1024];  // all loads in flight
#pragma unroll
    for (int jj = 0; jj < 8; ++jj) {
      union {
        __bf16 b8[8];
        uint4 u;
      } pk;
#pragma unroll
      for (int j = 0; j < 8; ++j) pk.b8[j] = (__bf16)fv[jj * 8 + j];
      *(uint4*)(dst + jj * 8) = pk.u;
    }
  } else {
    // ---- wt_prep: OIHW fp32 -> [o][kt*64 + p*8 + e] bf16, swizzle baked ---
    const int bb = bx - 1703;  // 0..1023
    const int o = bb & 511;
    const float* w = (bb >> 9) ? w2 : w1;
    __bf16* wt = (bb >> 9) ? wt2 : wt1;
#pragma unroll
    for (int i = 0; i < 18; ++i)
      Lw[t + 256 * i] = w[(size_t)o * 4608 + t + 256 * i];
    __syncthreads();
#pragma unroll
    for (int i = 0; i < 18; ++i) {
      const int idk = t + 256 * i;
      const int kt = idk >> 6;
      const int p = (idk >> 3) & 7, e = idk & 7;
      const int logical = p ^ (o & 7);
      const int k2 = kt * 64 + logical * 8 + e;
      const int tap = k2 >> 9, ci = k2 & 511;
      wt[(size_t)o * 4608 + idk] = (__bf16)Lw[ci * 9 + tap];
    }
  }
}

// ---------------------------------------------------------------------------
extern "C" void kernel_launch(void* const* d_in, const int* in_sizes, int n_in,
                              void* d_out, int out_size, void* d_ws,
                              size_t ws_size, hipStream_t stream) {
  const float* x = (const float*)d_in[0];
  const float* w1 = (const float*)d_in[1];
  const float* gam = (const float*)d_in[2];
  const float* bet = (const float*)d_in[3];
  const float* mean = (const float*)d_in[4];
  const float* var = (const float*)d_in[5];
  const float* w2 = (const float*)d_in[6];
  const float* wA = (const float*)d_in[7];
  const float* cent = (const float*)d_in[8];
  float* out = (float*)d_out;

  char* ws = (char*)d_ws;
  __bf16* Wt1 = (__bf16*)(ws + 0);          // 4,718,592 (dead after conv1)
  __bf16* Wt2 = (__bf16*)(ws + 4718592);    // 4,718,592 (dead after conv2)
  __bf16* xpad = (__bf16*)(ws + 9437184);   // 18,939,904 (dead after conv1)
  __bf16* xebT = (__bf16*)(ws + 9437184);   // alias: 16,777,216 (conv2 out)
  __bf16* saPb = (__bf16*)(ws + 26214400);  // 2,097,152
  __bf16* hpad = (__bf16*)(ws + 28377088);  // 18,939,904 (dead after conv2)
  __bf16* xeb = (__bf16*)(ws + 28377088);   // alias: 16,777,216 (expand out)
  float* vpart = (float*)(ws + 0);          // alias Wt1/2: 8,388,608
  float* vraw = (float*)(ws + 8388608);     // alias: 2,097,152
  float* scale = (float*)(ws + 47316992);   // 2048 B
  float* shift = (float*)(ws + 47319040);   // 2048 B
  __bf16* watb = (__bf16*)(ws + 47321088);  // 65,536 B
  float* S = (float*)(ws + 47386624);       // 4096 B
  float* gss = (float*)(ws + 47390720);     // 64 B

  float* xenc = out + 524288;  // output 1 (x_enc, fp32 NCHW)

  prep_all<<<2727, 256, 0, stream>>>(x, w1, w2, gam, bet, mean, var, wA, xpad,
                                     hpad, Wt1, Wt2, scale, shift, watb, S);

  conv_gemm<0><<<dim3(128, 4), 256, 0, stream>>>(xpad, Wt1, scale, shift, hpad);
  conv_gemm<1><<<dim3(128, 4), 256, 0, stream>>>(hpad, Wt2, nullptr, nullptr,
                                                 xebT);

  post_conv<<<2304, 256, 0, stream>>>(xebT, watb, saPb, S, xenc, xeb);
  vlad_gemm<<<dim3(4, 16, 4), 256, 0, stream>>>(saPb, xeb, vpart);
  intra_norm<<<1024, 64, 0, stream>>>(vraw, vpart, S, cent, gss);
  finalize<<<2048, 256, 0, stream>>>(vraw, gss, out);
}

// Round 7
// 307.033 us; speedup vs baseline: 1.0704x; 1.0412x over previous
//
#include <hip/hip_runtime.h>
#include <math.h>

// ---------------------------------------------------------------------------
// NetVLAD on gfx950.
// conv1/conv2: implicit GEMM, v_mfma_f32_16x16x32_bf16, 128x128 tile, BK=64,
//   2 blocks/CU — FROZEN at the round-3-measured structure (76.9 us x2):
//   W double-buffer, TWO barriers per step, counted vmcnt(4), W(s+2) in
//   flight across barriers, halo(cc+1) FIFO-first at tap==8, T5 setprio.
//   (Round-2 256x128 tile: latency-bound, -55%. Round-6 W triple-buffer
//   +1 barrier/step: LDS port contention between drifted blocks, -17%.
//   Conv experiments frozen; the 2-barrier package is load-bearing.)
// post_conv: fused assign_softmax (256 blocks, first) + expand_x (2048
//   blocks) — independent work, one launch, latency/BW overlap.
// vlad: 4-deep LDS multibuffer, counted vmcnt. prep_all: fused prep.
// Fragment layouts (HW-verified): A/B: idx=lane&15, k=(lane>>4)*8+j;
// C/D: col=lane&15 (B idx), row=(lane>>4)*4+reg (A idx).
// ---------------------------------------------------------------------------

typedef __bf16 bf16x8 __attribute__((ext_vector_type(8)));
typedef float f32x4 __attribute__((ext_vector_type(4)));

#define GLDS16(gp, lp)                                                  \
  __builtin_amdgcn_global_load_lds(                                     \
      (const __attribute__((address_space(1))) void*)(gp),              \
      (__attribute__((address_space(3))) void*)(lp), 16, 0, 0)

// ---------------- conv as implicit GEMM, halo-tiled, BK=64 -----------------
// grid (128 pixel-tiles, 4 o-tiles), block 256 = 4 waves (2x2)
// MODE 0: BN+ReLU -> padded NHWC bf16 (hpad).
// MODE 1: xebT bf16 [n][pix][512] (c-contiguous), no BN.
template <int MODE>
__global__ __launch_bounds__(256) void conv_gemm(
    const __bf16* __restrict__ in,  // padded NHWC bf16 [16][34][34][512]
    const __bf16* __restrict__ wt,  // prepacked+swizzled [512][72*64]
    const float* __restrict__ scale, const float* __restrict__ shift,
    __bf16* __restrict__ outp) {
  __shared__ __align__(16) __bf16 Hl[6 * 42 * 64];   // 16128 elem, 31.5 KB
  __shared__ __align__(16) __bf16 Wl[2 * 128 * 64];  // 32 KB (double-buffered)

  const int t = threadIdx.x;
  const int bx = blockIdx.x, oT = blockIdx.y;
  const int lane = t & 63, wid = t >> 6;
  const int l16 = lane & 15, q = lane >> 4;
  const int wrow = wid >> 1, wcol = wid & 1;

  const int n = bx >> 3;
  const int trow0 = (bx & 7) * 4;  // first pixel row of this 128-pixel tile

  // ---- W staging: 4 chunks/thread; Wl[buf][row][phys8] = row*64 + phys*8
  const int swr = t >> 3, sp = t & 7;
  const __bf16* wsrc[4];
#pragma unroll
  for (int i = 0; i < 4; ++i)
    wsrc[i] = wt + (size_t)(oT * 128 + 32 * i + swr) * 4608 + sp * 8;

  // ---- halo staging: 8 chunks/thread over 6 rows x 42 cols x 8 c8-chunks
  const __bf16* inb = in + (size_t)n * (1156 * 512);
  const __bf16* hsrc[8];
  bool hval[8];
#pragma unroll
  for (int i = 0; i < 8; ++i) {
    const int jj = t + 256 * i;
    hval[i] = jj < 2016;
    const int hr = jj / 336;
    const int hrem = jj - hr * 336;
    const int hw = hrem >> 3, hc8 = hrem & 7;
    hsrc[i] = inb + ((size_t)((trow0 + hr) * 34 + hw)) * 512 +
              (hc8 ^ (hw & 7)) * 8;
  }

  // ---- fragment read constants
  const int c0 = (q ^ (l16 & 7)) * 8;
  const int c1 = ((4 + q) ^ (l16 & 7)) * 8;
  int aoff[4], prow_[4], pcol_[4];
#pragma unroll
  for (int i = 0; i < 4; ++i) {
    aoff[i] = (wrow * 64 + i * 16 + l16) * 64;
    const int p = wcol * 64 + i * 16 + l16;
    prow_[i] = p >> 5;
    pcol_[i] = p & 31;
  }

  f32x4 acc[4][4];
#pragma unroll
  for (int i = 0; i < 4; ++i)
#pragma unroll
    for (int j = 0; j < 4; ++j) acc[i][j] = (f32x4){0.f, 0.f, 0.f, 0.f};

  // ---- prologue: halo(cc=0), W(step0)->Wl[0], W(step1)->Wl[1] ------------
  // step s has (cc,tap) = (s/9, s%9); woffs = (tap*8+cc)*64.
#pragma unroll
  for (int i = 0; i < 8; ++i)
    if (hval[i]) GLDS16(hsrc[i], Hl + (t + 256 * i) * 8);
#pragma unroll
  for (int i = 0; i < 4; ++i)
    GLDS16(wsrc[i], Wl + (t + 256 * i) * 8);  // step0: woffs=0
#pragma unroll
  for (int i = 0; i < 4; ++i)
    GLDS16(wsrc[i] + 512, Wl + 8192 + (t + 256 * i) * 8);  // step1: woffs=512
  // outstanding: halo(8) + W0(4) + W1(4). Wait halo+W0; keep W1 in flight.
  asm volatile("s_waitcnt vmcnt(4)" ::: "memory");
  __builtin_amdgcn_s_barrier();

  int tap = 0, dh = 0, dw = 0, cc = 0;  // step s
  int tap2 = 2, cc2 = 0;                // step s+2 (prefetch target)

#pragma unroll 1
  for (int s = 0; s < 72; ++s) {
    const int buf = (s & 1) << 13;  // 0 or 8192 elements
    const __bf16* Wb = Wl + buf;

    // A: fragment reads for step s
    bf16x8 aw[4][2], bp[4][2];
#pragma unroll
    for (int i = 0; i < 4; ++i) {
      aw[i][0] = *(const bf16x8*)&Wb[aoff[i] + c0];
      aw[i][1] = *(const bf16x8*)&Wb[aoff[i] + c1];
    }
#pragma unroll
    for (int i = 0; i < 4; ++i) {
      const int col = pcol_[i] + dw;
      const int rb = (prow_[i] + dh) * 2688 + col * 64;
      const int xr = col & 7;
      bp[i][0] = *(const bf16x8*)&Hl[rb + (q ^ xr) * 8];
      bp[i][1] = *(const bf16x8*)&Hl[rb + ((4 + q) ^ xr) * 8];
    }
    // B/C: reads landed in regs (cross-wave WAR vs incoming DMA), then sync.
    asm volatile("s_waitcnt lgkmcnt(0)" ::: "memory");
    __builtin_amdgcn_sched_barrier(0);
    __builtin_amdgcn_s_barrier();

    // D: issue next-halo FIRST (FIFO: so vmcnt(4) below covers it), then
    //    W(s+2) into the buffer step s just finished reading.
    if (tap == 8 && cc < 7) {
#pragma unroll
      for (int i = 0; i < 8; ++i)
        if (hval[i]) GLDS16(hsrc[i] + (cc + 1) * 64, Hl + (t + 256 * i) * 8);
    }
    if (s < 70) {
      const int woffs2 = (tap2 * 8 + cc2) * 64;
#pragma unroll
      for (int i = 0; i < 4; ++i)
        GLDS16(wsrc[i] + woffs2, Wl + buf + (t + 256 * i) * 8);
    }

    // E: MFMA cluster (T5)
    __builtin_amdgcn_s_setprio(1);
#pragma unroll
    for (int kh = 0; kh < 2; ++kh)
#pragma unroll
      for (int mt = 0; mt < 4; ++mt)
#pragma unroll
        for (int nt = 0; nt < 4; ++nt)
          acc[mt][nt] = __builtin_amdgcn_mfma_f32_16x16x32_bf16(
              aw[mt][kh], bp[nt][kh], acc[mt][nt], 0, 0, 0);
    __builtin_amdgcn_s_setprio(0);

    // F/G: counted wait — drain {W(s+1), halo-if-issued}; W(s+2) stays in
    // flight across the barrier. Tail drains fully.
    if (s < 70)
      asm volatile("s_waitcnt vmcnt(4)" ::: "memory");
    else
      asm volatile("s_waitcnt vmcnt(0)" ::: "memory");
    __builtin_amdgcn_s_barrier();

    // advance step / prefetch counters
    ++tap;
    ++dw;
    if (dw == 3) {
      dw = 0;
      ++dh;
    }
    if (tap == 9) {
      tap = 0;
      dh = 0;
      dw = 0;
      ++cc;
    }
    if (++tap2 == 9) {
      tap2 = 0;
      ++cc2;
    }
  }

  // ---- epilogue ----
#pragma unroll
  for (int nt = 0; nt < 4; ++nt) {
    const int m_l = wcol * 64 + nt * 16 + l16;
    const int mg2 = bx * 128 + m_l;
    const int n2 = mg2 >> 10, pix2 = mg2 & 1023;
#pragma unroll
    for (int mt = 0; mt < 4; ++mt) {
      const int ob = oT * 128 + wrow * 64 + mt * 16 + q * 4;
      f32x4 v = acc[mt][nt];
      union {
        __bf16 b[4];
        uint2 u;
      } pk;
      if (MODE == 0) {
        const f32x4 sc = *(const f32x4*)&scale[ob];
        const f32x4 sh = *(const f32x4*)&shift[ob];
#pragma unroll
        for (int r = 0; r < 4; ++r)
          pk.b[r] = (__bf16)fmaxf(v[r] * sc[r] + sh[r], 0.f);
        __bf16* dst = outp +
                      ((size_t)n2 * 1156 + ((pix2 >> 5) + 1) * 34 +
                       ((pix2 & 31) + 1)) * 512 + ob;
        *(uint2*)dst = pk.u;
      } else {
#pragma unroll
        for (int r = 0; r < 4; ++r) pk.b[r] = (__bf16)v[r];
        __bf16* dst = outp + ((size_t)n2 * 1024 + pix2) * 512 + ob;
        *(uint2*)dst = pk.u;
      }
    }
  }
}

// ---------------- fused post-conv2: assign_softmax + expand_x --------------
// bx < 256: assign_softmax (latency-bound long pole — dispatched first).
// bx >= 256: expand_x (BW-bound, fills remaining CUs).
__global__ __launch_bounds__(256) void post_conv(
    const __bf16* __restrict__ xebT, const __bf16* __restrict__ watb,
    __bf16* __restrict__ saPb, float* __restrict__ S,
    float* __restrict__ xenc, __bf16* __restrict__ xeb) {
  __shared__ __align__(16) __bf16 Al[4][64 * 32];
  __shared__ __align__(16) __bf16 Wlb[4][64 * 32];
  __shared__ float Sl[64];
  const int t = threadIdx.x;
  const int bx0 = blockIdx.x;

  if (bx0 < 256) {
    // ======== assign_softmax (4-deep pipeline) ========
    const int pt = bx0 & 15, n = bx0 >> 4;
    const int lane = t & 63, wid = t >> 6;
    const int l16 = lane & 15, q = lane >> 4;
    if (t < 64) Sl[t] = 0.f;

    const int arow = t >> 2;  // pixel row 0..63
    const __bf16* asrc = xebT + ((size_t)n * 1024 + pt * 64 + arow) * 512 +
                         ((t & 3) ^ ((arow >> 1) & 3)) * 8;
    const __bf16* wsrc = watb + (size_t)(t >> 2) * 512 + (t & 3) * 8;
    const int ldsb = wid * 512;
    const int sw = (q ^ ((l16 >> 1) & 3)) * 8;
    const int pnoff = (t >> 2) * 32 + (t & 3) * 8;

    f32x4 acc[4];
#pragma unroll
    for (int i = 0; i < 4; ++i) acc[i] = (f32x4){0.f, 0.f, 0.f, 0.f};
    float pn = 0.f;

#pragma unroll
    for (int p = 0; p < 3; ++p) {
      GLDS16(asrc + p * 32, (__bf16*)Al[p] + ldsb);
      GLDS16(wsrc + p * 32, (__bf16*)Wlb[p] + ldsb);
    }
    asm volatile("s_waitcnt vmcnt(4)" ::: "memory");
    __builtin_amdgcn_s_barrier();

#pragma unroll 1
    for (int kc = 0; kc < 16; ++kc) {
      const __bf16* Ab = Al[kc & 3];
      const __bf16* Wb = Wlb[kc & 3];
      bf16x8 pv = *(const bf16x8*)&Ab[pnoff];
      bf16x8 pf = *(const bf16x8*)&Ab[(wid * 16 + l16) * 32 + sw];
      bf16x8 wf[4];
#pragma unroll
      for (int ka = 0; ka < 4; ++ka)
        wf[ka] = *(const bf16x8*)&Wb[(ka * 16 + l16) * 32 + sw];
      asm volatile("s_waitcnt lgkmcnt(0)" ::: "memory");
      __builtin_amdgcn_sched_barrier(0);
      __builtin_amdgcn_s_barrier();
      if (kc + 3 < 16) {
        GLDS16(asrc + (kc + 3) * 32, (__bf16*)Al[(kc + 3) & 3] + ldsb);
        GLDS16(wsrc + (kc + 3) * 32, (__bf16*)Wlb[(kc + 3) & 3] + ldsb);
      }
#pragma unroll
      for (int j = 0; j < 8; ++j) {
        float f = (float)pv[j];
        pn = fmaf(f, f, pn);
      }
#pragma unroll
      for (int ka = 0; ka < 4; ++ka)
        acc[ka] = __builtin_amdgcn_mfma_f32_16x16x32_bf16(wf[ka], pf, acc[ka],
                                                          0, 0, 0);
      if (kc < 13)
        asm volatile("s_waitcnt vmcnt(4)" ::: "memory");
      else
        asm volatile("s_waitcnt vmcnt(0)" ::: "memory");
      __builtin_amdgcn_s_barrier();
    }
    pn += __shfl_xor(pn, 1);
    pn += __shfl_xor(pn, 2);
    const float rn = 1.0f / fmaxf(sqrtf(__shfl(pn, l16 * 4)), 1e-12f);

    float sc[16];
    float m = -3.4e38f;
#pragma unroll
    for (int ka = 0; ka < 4; ++ka)
#pragma unroll
      for (int r = 0; r < 4; ++r) {
        float v = acc[ka][r] * rn;
        sc[ka * 4 + r] = v;
        m = fmaxf(m, v);
      }
    m = fmaxf(m, __shfl_xor(m, 16));
    m = fmaxf(m, __shfl_xor(m, 32));
    float s = 0.f;
#pragma unroll
    for (int j = 0; j < 16; ++j) {
      sc[j] = __expf(sc[j] - m);
      s += sc[j];
    }
    s += __shfl_xor(s, 16);
    s += __shfl_xor(s, 32);
    const float inv = 1.0f / s;
    const int pixg = pt * 64 + wid * 16 + l16;
#pragma unroll
    for (int j = 0; j < 16; ++j) {
      const int k = (j >> 2) * 16 + q * 4 + (j & 3);
      float sa = sc[j] * inv;
      sc[j] = sa;
      saPb[((size_t)n * 64 + k) * 1024 + pixg] = (__bf16)(sa * rn);
    }
#pragma unroll
    for (int j = 0; j < 16; ++j) {
      float v = sc[j];
      v += __shfl_xor(v, 1);
      v += __shfl_xor(v, 2);
      v += __shfl_xor(v, 4);
      v += __shfl_xor(v, 8);
      sc[j] = v;
    }
    if (l16 == 0) {
#pragma unroll
      for (int j = 0; j < 16; ++j)
        atomicAdd(&Sl[(j >> 2) * 16 + q * 4 + (j & 3)], sc[j]);
    }
    __syncthreads();
    if (t < 64) atomicAdd(&S[n * 64 + t], Sl[t]);
  } else {
    // ======== expand_x: xebT [pix][c] -> xenc fp32 [c][pix] + xeb bf16 ====
    const int e = bx0 - 256;
    const int cc = e & 7, ptile = (e >> 3) & 15, n = e >> 7;
    __bf16* Ll = (__bf16*)Al;  // 8 KB carve
    const int p0 = ptile * 64, c0 = cc * 64;
#pragma unroll
    for (int i = 0; i < 2; ++i) {
      const int u = t * 2 + i;
      const int pix = u >> 3, c8 = u & 7;
      uint4 v = *(const uint4*)&xebT[((size_t)n * 1024 + p0 + pix) * 512 + c0 +
                                     c8 * 8];
      *(uint4*)&Ll[pix * 64 + (c8 ^ (pix & 7)) * 8] = v;
    }
    __syncthreads();
    const int c = t >> 2, g = t & 3;
    union {
      float f[4];
      float4 v;
    } fv[4];
    union {
      __bf16 b[16];
      uint4 u[2];
    } bv;
#pragma unroll
    for (int r = 0; r < 16; ++r) {
      const int pix = g * 16 + r;
      __bf16 b = Ll[pix * 64 + ((c >> 3) ^ (pix & 7)) * 8 + (c & 7)];
      bv.b[r] = b;
      fv[r >> 2].f[r & 3] = (float)b;
    }
    float* fd = xenc + ((size_t)n * 512 + c0 + c) * 1024 + p0 + g * 16;
#pragma unroll
    for (int r = 0; r < 4; ++r) *(float4*)(fd + r * 4) = fv[r].v;
    __bf16* bd = xeb + ((size_t)n * 512 + c0 + c) * 1024 + p0 + g * 16;
    *(uint4*)bd = bv.u[0];
    *(uint4*)(bd + 8) = bv.u[1];
  }
}

// ---------------- VLAD aggregation: bf16 MFMA GEMM (4-deep pipeline) -------
__global__ __launch_bounds__(256) void vlad_gemm(
    const __bf16* __restrict__ saPb, const __bf16* __restrict__ xeb,
    float* __restrict__ vpart) {
  __shared__ __align__(16) __bf16 Al[4][64 * 32];
  __shared__ __align__(16) __bf16 Bl[4][128 * 32];

  const int t = threadIdx.x;
  const int cT = blockIdx.x, n = blockIdx.y, ks = blockIdx.z;
  const int lane = t & 63, wid = t >> 6;
  const int l16 = lane & 15, q = lane >> 4;
  const int wrow = wid >> 1, wcol = wid & 1;

  const int ar = t >> 2, acp = t & 3;
  const __bf16* asrc = saPb + (size_t)n * 65536 + (size_t)ar * 1024 + ks * 256 +
                       (acp ^ ((ar >> 1) & 3)) * 8;
  const int br0 = t >> 2, bcp0 = t & 3;
  const int br1 = (t + 256) >> 2, bcp1 = t & 3;
  const __bf16* bsrc0 = xeb + (size_t)n * 524288 +
                        (size_t)(cT * 128 + br0) * 1024 + ks * 256 +
                        (bcp0 ^ ((br0 >> 1) & 3)) * 8;
  const __bf16* bsrc1 = xeb + (size_t)n * 524288 +
                        (size_t)(cT * 128 + br1) * 1024 + ks * 256 +
                        (bcp1 ^ ((br1 >> 1) & 3)) * 8;

  const int ldsb = wid * 512;
  const int sw = (q ^ ((l16 >> 1) & 3)) * 8;

  f32x4 acc[2][4];
#pragma unroll
  for (int i = 0; i < 2; ++i)
#pragma unroll
    for (int j = 0; j < 4; ++j) acc[i][j] = (f32x4){0.f, 0.f, 0.f, 0.f};

  // prologue: issue tiles 0..2 (3 loads each)
#pragma unroll
  for (int p = 0; p < 3; ++p) {
    GLDS16(asrc + p * 32, (__bf16*)Al[p] + ldsb);
    GLDS16(bsrc0 + p * 32, (__bf16*)Bl[p] + ldsb);
    GLDS16(bsrc1 + p * 32, (__bf16*)Bl[p] + 2048 + ldsb);
  }
  asm volatile("s_waitcnt vmcnt(6)" ::: "memory");  // tile0 done; 1,2 fly
  __builtin_amdgcn_s_barrier();

#pragma unroll 1
  for (int kc = 0; kc < 8; ++kc) {
    const __bf16* Ab = Al[kc & 3];
    const __bf16* Bb = Bl[kc & 3];
    // A: register reads
    bf16x8 af[2], bf[4];
#pragma unroll
    for (int i = 0; i < 2; ++i)
      af[i] = *(const bf16x8*)&Ab[(wrow * 32 + i * 16 + l16) * 32 + sw];
#pragma unroll
    for (int i = 0; i < 4; ++i)
      bf[i] = *(const bf16x8*)&Bb[(wcol * 64 + i * 16 + l16) * 32 + sw];
    // B: reads landed before buffer reuse
    asm volatile("s_waitcnt lgkmcnt(0)" ::: "memory");
    __builtin_amdgcn_sched_barrier(0);
    __builtin_amdgcn_s_barrier();
    // C: issue tile kc+3
    if (kc + 3 < 8) {
      GLDS16(asrc + (kc + 3) * 32, (__bf16*)Al[(kc + 3) & 3] + ldsb);
      GLDS16(bsrc0 + (kc + 3) * 32, (__bf16*)Bl[(kc + 3) & 3] + ldsb);
      GLDS16(bsrc1 + (kc + 3) * 32, (__bf16*)Bl[(kc + 3) & 3] + 2048 + ldsb);
    }
    // D: MFMA
#pragma unroll
    for (int mt = 0; mt < 2; ++mt)
#pragma unroll
      for (int nt = 0; nt < 4; ++nt)
        acc[mt][nt] = __builtin_amdgcn_mfma_f32_16x16x32_bf16(
            af[mt], bf[nt], acc[mt][nt], 0, 0, 0);
    // E/F: counted wait — tile kc+1 ready; kc+2, kc+3 stay in flight
    if (kc < 5)
      asm volatile("s_waitcnt vmcnt(6)" ::: "memory");
    else
      asm volatile("s_waitcnt vmcnt(0)" ::: "memory");
    __builtin_amdgcn_s_barrier();
  }

  float* vp = vpart + (size_t)(ks * 16 + n) * 32768;
#pragma unroll
  for (int mt = 0; mt < 2; ++mt) {
    const int krow = wrow * 32 + mt * 16 + q * 4;
#pragma unroll
    for (int nt = 0; nt < 4; ++nt) {
      const int ccol = cT * 128 + wcol * 64 + nt * 16 + l16;
#pragma unroll
      for (int r = 0; r < 4; ++r)
        vp[(size_t)(krow + r) * 512 + ccol] = acc[mt][nt][r];
    }
  }
}

// ---------------- intra-norm (sums 4 K-split partials) ---------------------
__global__ __launch_bounds__(64) void intra_norm(float* __restrict__ vraw,
                                                 const float* __restrict__ vpart,
                                                 const float* __restrict__ S,
                                                 const float* __restrict__ cent,
                                                 float* __restrict__ gss) {
  const int b = blockIdx.x;  // n*64 + k
  const int n = b >> 6, k = b & 63;
  const int lane = threadIdx.x;
  const float s = S[b];
  float v[8];
  float ss = 0.f;
#pragma unroll
  for (int j = 0; j < 8; ++j) {
    const int c = lane * 8 + j;
    const size_t off = (size_t)b * 512 + c;
    float val = vpart[off] + vpart[524288 + off] + vpart[2 * 524288 + off] +
                vpart[3 * 524288 + off] - s * cent[k * 512 + c];
    v[j] = val;
    ss += val * val;
  }
#pragma unroll
  for (int off = 1; off < 64; off <<= 1) ss += __shfl_xor(ss, off);
  const float rn = 1.0f / fmaxf(sqrtf(ss), 1e-12f);
#pragma unroll
  for (int j = 0; j < 8; ++j) vraw[(size_t)b * 512 + lane * 8 + j] = v[j] * rn;
  if (lane == 0) atomicAdd(&gss[n], ss * rn * rn);
}

__global__ __launch_bounds__(256) void finalize(const float* __restrict__ vraw,
                                                const float* __restrict__ gss,
                                                float* __restrict__ out) {
  const int base = blockIdx.x * 1024 + threadIdx.x;
#pragma unroll
  for (int j = 0; j < 4; ++j) {
    const int id = base + j * 256;
    const int n = id >> 15;
    out[id] = vraw[id] * (1.0f / fmaxf(sqrtf(gss[n]), 1e-12f));
  }
}

// ---------------- fused prep: zero_border + misc + xform + wt_prep ---------
// grid layout: [0,1056) zero-border, [1056,1191) misc, [1191,1703) xform,
// [1703,2727) wt_prep. All independent writes; fusing overlaps them across
// CUs and drops 3 launch gaps.
__global__ __launch_bounds__(256) void prep_all(
    const float* __restrict__ x, const float* __restrict__ w1,
    const float* __restrict__ w2, const float* __restrict__ g,
    const float* __restrict__ b, const float* __restrict__ m,
    const float* __restrict__ v, const float* __restrict__ wA,
    __bf16* __restrict__ xpad, __bf16* __restrict__ hpad,
    __bf16* __restrict__ wt1, __bf16* __restrict__ wt2,
    float* __restrict__ scale, float* __restrict__ shift,
    __bf16* __restrict__ watb, float* __restrict__ Sz) {
  __shared__ float Lw[4608];
  const int bx = blockIdx.x;
  const int t = threadIdx.x;

  if (bx < 1056) {
    // ---- zero the 132-pixel pad ring of xpad/hpad ----
    const int which = bx >= 528;
    const int id = (which ? bx - 528 : bx) * 256 + t;  // 0..135167
    const int n = id / 8448;
    const int rem = id - n * 8448;
    const int pb = rem >> 6;  // 0..131 border pixel
    const int c8 = rem & 63;
    int h, w;
    if (pb < 34) {
      h = 0;
      w = pb;
    } else if (pb < 68) {
      h = 33;
      w = pb - 34;
    } else {
      const int r2 = pb - 68;
      h = 1 + (r2 >> 1);
      w = (r2 & 1) * 33;
    }
    __bf16* base = which ? hpad : xpad;
    *(uint4*)(base + ((size_t)n * 1156 + h * 34 + w) * 512 + c8 * 8) =
        (uint4){0u, 0u, 0u, 0u};
  } else if (bx < 1191) {
    // ---- misc: BN fold, watb swizzle, S zero ----
    const int i = (bx - 1056) * 256 + t;
    if (i < 512) {
      float sc = g[i] / sqrtf(v[i] + 1e-5f);
      scale[i] = sc;
      shift[i] = b[i] - m[i] * sc;
    } else if (i < 512 + 32768) {
      const int id = i - 512;
      const int k = id >> 9, j = id & 511;
      const int kt = j >> 5, cpos = (j >> 3) & 3, e = j & 7;
      const int c = kt * 32 + (cpos ^ ((k >> 1) & 3)) * 8 + e;
      watb[(size_t)k * 512 + j] = (__bf16)wA[(size_t)k * 512 + c];
    } else if (i < 512 + 32768 + 1040) {
      Sz[i - (512 + 32768)] = 0.f;
    }
  } else if (bx < 1703) {
    // ---- xform: x (fp32 NCHW) -> xpad (bf16 NHWC padded) ----
    const int bb = bx - 1191;
    const int n = bb >> 5, h = bb & 31;
    const int w = t & 31, cg = t >> 5;
    const float* src = x + ((size_t)n * 512 + cg * 64) * 1024 + h * 32 + w;
    __bf16* dst =
        xpad + ((size_t)n * 1156 + (h + 1) * 34 + (w + 1)) * 512 + cg * 64;
    float fv[64];
#pragma unroll
    for (int j = 0; j < 64; ++j) fv[j] = src[j * 1024];  // all loads in flight
#pragma unroll
    for (int jj = 0; jj < 8; ++jj) {
      union {
        __bf16 b8[8];
        uint4 u;
      } pk;
#pragma unroll
      for (int j = 0; j < 8; ++j) pk.b8[j] = (__bf16)fv[jj * 8 + j];
      *(uint4*)(dst + jj * 8) = pk.u;
    }
  } else {
    // ---- wt_prep: OIHW fp32 -> [o][kt*64 + p*8 + e] bf16, swizzle baked ---
    const int bb = bx - 1703;  // 0..1023
    const int o = bb & 511;
    const float* w = (bb >> 9) ? w2 : w1;
    __bf16* wt = (bb >> 9) ? wt2 : wt1;
#pragma unroll
    for (int i = 0; i < 18; ++i)
      Lw[t + 256 * i] = w[(size_t)o * 4608 + t + 256 * i];
    __syncthreads();
#pragma unroll
    for (int i = 0; i < 18; ++i) {
      const int idk = t + 256 * i;
      const int kt = idk >> 6;
      const int p = (idk >> 3) & 7, e = idk & 7;
      const int logical = p ^ (o & 7);
      const int k2 = kt * 64 + logical * 8 + e;
      const int tap = k2 >> 9, ci = k2 & 511;
      wt[(size_t)o * 4608 + idk] = (__bf16)Lw[ci * 9 + tap];
    }
  }
}

// ---------------------------------------------------------------------------
extern "C" void kernel_launch(void* const* d_in, const int* in_sizes, int n_in,
                              void* d_out, int out_size, void* d_ws,
                              size_t ws_size, hipStream_t stream) {
  const float* x = (const float*)d_in[0];
  const float* w1 = (const float*)d_in[1];
  const float* gam = (const float*)d_in[2];
  const float* bet = (const float*)d_in[3];
  const float* mean = (const float*)d_in[4];
  const float* var = (const float*)d_in[5];
  const float* w2 = (const float*)d_in[6];
  const float* wA = (const float*)d_in[7];
  const float* cent = (const float*)d_in[8];
  float* out = (float*)d_out;

  char* ws = (char*)d_ws;
  __bf16* Wt1 = (__bf16*)(ws + 0);          // 4,718,592 (dead after conv1)
  __bf16* Wt2 = (__bf16*)(ws + 4718592);    // 4,718,592 (dead after conv2)
  __bf16* xpad = (__bf16*)(ws + 9437184);   // 18,939,904 (dead after conv1)
  __bf16* xebT = (__bf16*)(ws + 9437184);   // alias: 16,777,216 (conv2 out)
  __bf16* saPb = (__bf16*)(ws + 26214400);  // 2,097,152
  __bf16* hpad = (__bf16*)(ws + 28377088);  // 18,939,904 (dead after conv2)
  __bf16* xeb = (__bf16*)(ws + 28377088);   // alias: 16,777,216 (expand out)
  float* vpart = (float*)(ws + 0);          // alias Wt1/2: 8,388,608
  float* vraw = (float*)(ws + 8388608);     // alias: 2,097,152
  float* scale = (float*)(ws + 47316992);   // 2048 B
  float* shift = (float*)(ws + 47319040);   // 2048 B
  __bf16* watb = (__bf16*)(ws + 47321088);  // 65,536 B
  float* S = (float*)(ws + 47386624);       // 4096 B
  float* gss = (float*)(ws + 47390720);     // 64 B

  float* xenc = out + 524288;  // output 1 (x_enc, fp32 NCHW)

  prep_all<<<2727, 256, 0, stream>>>(x, w1, w2, gam, bet, mean, var, wA, xpad,
                                     hpad, Wt1, Wt2, scale, shift, watb, S);

  conv_gemm<0><<<dim3(128, 4), 256, 0, stream>>>(xpad, Wt1, scale, shift, hpad);
  conv_gemm<1><<<dim3(128, 4), 256, 0, stream>>>(hpad, Wt2, nullptr, nullptr,
                                                 xebT);

  post_conv<<<2304, 256, 0, stream>>>(xebT, watb, saPb, S, xenc, xeb);
  vlad_gemm<<<dim3(4, 16, 4), 256, 0, stream>>>(saPb, xeb, vpart);
  intra_norm<<<1024, 64, 0, stream>>>(vraw, vpart, S, cent, gss);
  finalize<<<512, 256, 0, stream>>>(vraw, gss, out);
}